// Round 10
// baseline (304.029 us; speedup 1.0000x reference)
//
#include <hip/hip_runtime.h>

// ---------------- problem constants ----------------
#define EE 200000
#define VV 50000
#define LN 128
#define KD 256     // 2*LN
#define SS 32
#define NN 1024    // SS*SS
#define CC 10
#define MUS 0.028125f   // MU/S = 0.9/32

typedef short short8_t __attribute__((ext_vector_type(8)));
typedef float f32x4 __attribute__((ext_vector_type(4)));

__device__ __forceinline__ unsigned short f32_to_bf16_rne(float f) {
    union { float f; unsigned u; } x; x.f = f;
    unsigned r = x.u + 0x7FFFu + ((x.u >> 16) & 1u);
    return (unsigned short)(r >> 16);
}

__device__ __forceinline__ float bf16_to_f32(unsigned short h) {
    union { unsigned u; float f; } x; x.u = ((unsigned)h) << 16; return x.f;
}

__device__ __forceinline__ float tanh_fast(float x) {
    float t = __builtin_amdgcn_exp2f(x * 2.885390081777927f);
    return 1.0f - 2.0f * __builtin_amdgcn_rcpf(t + 1.0f);
}

// Pade(3,2): validated R3/R5/R7/R8/R9 (absmax 0.0156 vs 6.8e-2 thr).
__device__ __forceinline__ float ptanh(float x) {
    float x2 = x * x;
    return x * (27.f + x2) * __builtin_amdgcn_rcpf(27.f + 9.f * x2);
}

__device__ __forceinline__ void load_lds16(const void* g, void* l) {
    __builtin_amdgcn_global_load_lds(
        (const __attribute__((address_space(1))) unsigned int*)g,
        (__attribute__((address_space(3))) unsigned int*)l,
        16, 0, 0);
}

// ---------------- K_prep: featB | WxiB | bxiT | hist | R ----------------
__global__ void k_prep(const float* __restrict__ feat, unsigned short* __restrict__ featB,
                       const float* __restrict__ Wxi, unsigned short* __restrict__ WxiB,
                       const float* __restrict__ bxi, float* __restrict__ bxiT,
                       const int* __restrict__ Xn, int* __restrict__ cnt,
                       const float* __restrict__ Wrou, const float* __restrict__ brou,
                       float* __restrict__ R) {
    int b = blockIdx.x, tid = threadIdx.x;
    if (b < 6250) {
        int idx = b * 256 + tid;                       // VV*LN/4
        float4 v = ((const float4*)feat)[idx];
        ushort4 o;
        o.x = f32_to_bf16_rne(v.x); o.y = f32_to_bf16_rne(v.y);
        o.z = f32_to_bf16_rne(v.z); o.w = f32_to_bf16_rne(v.w);
        ((ushort4*)featB)[idx] = o;
    } else if (b < 7274) {
        int idx = (b - 6250) * 256 + tid;              // KD*NN
        int k = idx >> 10, ncol = idx & 1023;
        int np = ((ncol & 31) << 5) | (ncol >> 5);     // n' = j*32+i
        WxiB[((size_t)(k >> 3) * NN + np) * 8 + (k & 7)] = f32_to_bf16_rne(Wxi[idx]);
    } else if (b == 7274) {
        #pragma unroll
        for (int it = 0; it < 4; ++it) {
            int i = it * 256 + tid;
            bxiT[i] = bxi[(i & 31) * 32 + (i >> 5)];
        }
    } else if (b < 8057) {
        int e = (b - 7275) * 256 + tid;
        if (e < EE) atomicAdd(&cnt[Xn[e]], 1);
    } else {
        int gid = (b - 8057) * 256 + tid;              // VV*SS
        int u = gid >> 5, s = gid & 31;
        const float* fr = feat + (size_t)u * LN;
        float a = brou[s];
        #pragma unroll 8
        for (int k = 0; k < LN; ++k) a += fr[k] * Wrou[k * SS + s];
        R[gid] = tanh_fast(a);
    }
}

// ---------------- K_scan_lb: single-pass decoupled-lookback exclusive scan ----------------
__global__ void __launch_bounds__(256) k_scan_lb(const int* __restrict__ cnt,
                                                 int* __restrict__ rowptr,
                                                 int* __restrict__ cursor,
                                                 unsigned int* flags) {
    __shared__ int s[256];
    __shared__ int bp;
    int b = blockIdx.x, tid = threadIdx.x;
    int i = b * 256 + tid;
    int x = (i < VV) ? cnt[i] : 0;
    s[tid] = x; __syncthreads();
    int v = x;
    #pragma unroll
    for (int off = 1; off < 256; off <<= 1) {
        int t = (tid >= off) ? s[tid - off] : 0;
        __syncthreads();
        v += t; s[tid] = v;
        __syncthreads();
    }
    int agg = s[255];

    if (b == 0) {
        if (tid == 0) {
            bp = 0;
            atomicExch(&flags[0], 0x80000000u | (unsigned)agg);
        }
    } else {
        if (tid == 0)
            atomicExch(&flags[b], 0x40000000u | (unsigned)agg);
        if (tid < 64) {
            int lane = tid;
            int base = b - 1;
            int pref = 0;
            while (true) {
                int idx = base - lane;
                unsigned wv;
                if (idx >= 0) {
                    do { wv = atomicAdd(&flags[idx], 0u); } while ((wv & 0xC0000000u) == 0u);
                } else {
                    wv = 0x80000000u;
                }
                bool isP = (wv >= 0x80000000u);
                unsigned long long bal = __ballot(isP);
                int Lp = bal ? __builtin_ctzll(bal) : 64;
                int val = (int)(wv & 0x3FFFFFFFu);
                int contrib = (lane < Lp) ? val : ((lane == Lp && bal) ? val : 0);
                #pragma unroll
                for (int o = 1; o < 64; o <<= 1) contrib += __shfl_xor(contrib, o);
                pref += contrib;
                if (bal) break;
                base -= 64;
            }
            if (lane == 0) {
                bp = pref;
                atomicExch(&flags[b], 0x80000000u | (unsigned)(pref + agg));
            }
        }
    }
    __syncthreads();
    int excl = v - x + bp;
    if (i < VV) { rowptr[i] = excl; cursor[i] = excl; }
    if (b == 0 && tid == 0) rowptr[VV] = EE;
}

__global__ void k_scatter(const int* __restrict__ Xn, int* __restrict__ cursor,
                          int* __restrict__ perm) {
    int e = blockIdx.x * 256 + threadIdx.x;
    if (e < EE) {
        int p = atomicAdd(&cursor[Xn[e]], 1);
        perm[p] = e;
    }
}

// ---------------- K4: He[e][i] = scale_e * sum_j ptanh(S[e][i,j]+bx) * h_e[j] ----------------
// wave = 32 edges x full N; half-chunk (8KB) staging, 2 slots, 1-deep acc,
// occupancy-first: LDS 34.8KB (4 blocks/CU) + regs<=~112 (4 waves/SIMD).
__global__ void __launch_bounds__(256, 4)
k_edge_gemm(const unsigned short* __restrict__ featB, const unsigned short* __restrict__ WxiB,
            const int* __restrict__ Xn, const int* __restrict__ Xe,
            const float* __restrict__ dg, const float* __restrict__ bxiT,
            const int* __restrict__ perm, const float* __restrict__ R,
            const int* __restrict__ rowptr, unsigned short* __restrict__ HeB) {
    __shared__ __align__(16) unsigned short Bs[2 * 4096];   // 2 slots x 8 KB (half-chunk)
    __shared__ float hs[128][33];                           // 16.9 KB
    __shared__ int   us[128], vs[128];
    __shared__ float scale_s[128];                          // total 34,816 B -> 4 blocks/CU

    const int tid = threadIdx.x;
    const int eb = blockIdx.x * 128;

    // half-chunk staging: unit U in [0,512), 16B each; thread does U=tid, U=256+tid
    // gbyte(c,h,U) = h*262144 + (U>>5)*16384 + c*512 + (U&31)*16
    // ldsbyte(slot,U) = slot*8192 + U*16
    const size_t gq0 = (size_t)((tid >> 5) * 16384 + (tid & 31) * 16);
    const int d0 = tid * 16;

#define STAGE_H(cc, hh, slot) { \
    const char* gs_ = (const char*)WxiB + (size_t)(hh) * 262144 + (size_t)(cc) * 512 + gq0; \
    char* ld_ = (char*)Bs + (slot) * 8192 + d0; \
    load_lds16(gs_,          ld_); \
    load_lds16(gs_ + 131072, ld_ + 4096); }

    // stage chunk 0 first half immediately (critical path)
    STAGE_H(0, 0, 0);

    if (tid < 128) {
        int p = eb + tid; if (p > EE - 1) p = EE - 1;
        int e0 = perm[p];
        us[tid] = Xn[e0]; vs[tid] = Xe[e0];
        scale_s[tid] = MUS / dg[e0];
    }
    __syncthreads();

    const int w = tid >> 6, lane = tid & 63;
    const int g = lane >> 4, l15 = lane & 15;
    const int row0 = w * 32;

    // A fragments for 32 edges (64 regs)
    short8_t af[8][2];
    #pragma unroll
    for (int kk = 0; kk < 8; ++kk)
        #pragma unroll
        for (int mf = 0; mf < 2; ++mf) {
            int el = row0 + mf * 16 + l15;
            int node = (kk < 4) ? us[el] : vs[el];
            af[kk][mf] = *(const short8_t*)(featB + (size_t)node * LN + (kk & 3) * 32 + g * 8);
        }

    // hs[el][s] = cnt[u]*R[u][s]
    #pragma unroll
    for (int it = 0; it < 16; ++it) {
        int idx = it * 256 + tid;
        int el = idx >> 5, s2 = idx & 31;
        int u = us[el];
        float cnt = (float)(rowptr[u + 1] - rowptr[u]);
        hs[el][s2] = cnt * R[u * SS + s2];
    }
    __syncthreads();   // drains stage(0,h0) + publishes hs

    const char* bbase = (const char*)Bs + (g * 512 + l15 * 16);
    const f32x4 z4 = {0.f, 0.f, 0.f, 0.f};
    f32x4 acc[2][2], he[2][2];
    #pragma unroll
    for (int mf = 0; mf < 2; ++mf)
        #pragma unroll
        for (int f = 0; f < 2; ++f) he[mf][f] = z4;

#define SYNCPT() { \
    asm volatile("s_waitcnt vmcnt(0)" ::: "memory"); \
    __builtin_amdgcn_s_barrier(); \
    __builtin_amdgcn_sched_barrier(0); }

    #pragma unroll 1
    for (int c = 0; c < 32; ++c) {
        // ---- phase 1: stage 2nd half of c -> slot1 ; MFMA kk0..3 from slot0 (init) ----
        STAGE_H(c, 1, 1);
        #pragma unroll
        for (int kk = 0; kk < 4; ++kk) {
            short8_t b0 = *(const short8_t*)(bbase + kk * 2048);
            short8_t b1 = *(const short8_t*)(bbase + kk * 2048 + 256);
            #pragma unroll
            for (int mf = 0; mf < 2; ++mf) {
                acc[mf][0] = __builtin_amdgcn_mfma_f32_16x16x32_bf16(af[kk][mf], b0, kk ? acc[mf][0] : z4, 0, 0, 0);
                acc[mf][1] = __builtin_amdgcn_mfma_f32_16x16x32_bf16(af[kk][mf], b1, kk ? acc[mf][1] : z4, 0, 0, 0);
            }
        }
        SYNCPT();                        // slot1 staged; slot0 reads done block-wide

        // ---- phase 2: stage 1st half of c+1 -> slot0 ; MFMA kk4..7 from slot1 ; EPI(c) ----
        if (c < 31) STAGE_H(c + 1, 0, 0);
        #pragma unroll
        for (int kk = 4; kk < 8; ++kk) {
            short8_t b0 = *(const short8_t*)(bbase + 8192 + (kk - 4) * 2048);
            short8_t b1 = *(const short8_t*)(bbase + 8192 + (kk - 4) * 2048 + 256);
            #pragma unroll
            for (int mf = 0; mf < 2; ++mf) {
                acc[mf][0] = __builtin_amdgcn_mfma_f32_16x16x32_bf16(af[kk][mf], b0, acc[mf][0], 0, 0, 0);
                acc[mf][1] = __builtin_amdgcn_mfma_f32_16x16x32_bf16(af[kk][mf], b1, acc[mf][1], 0, 0, 0);
            }
        }
        {   // epilogue for chunk c (VALU covers stage flight; acc stall hidden by co-resident waves)
            float bx0 = bxiT[c * 32 + l15];
            float bx1 = bxiT[c * 32 + 16 + l15];
            #pragma unroll
            for (int mf = 0; mf < 2; ++mf)
                #pragma unroll
                for (int r = 0; r < 4; ++r) {
                    float hv = hs[row0 + mf * 16 + g * 4 + r][c];
                    he[mf][0][r] += ptanh(acc[mf][0][r] + bx0) * hv;
                    he[mf][1][r] += ptanh(acc[mf][1][r] + bx1) * hv;
                }
        }
        SYNCPT();                        // slot0 staged; slot1 reads done block-wide
    }

    // store He (sorted order), scaled
    #pragma unroll
    for (int mf = 0; mf < 2; ++mf)
        #pragma unroll
        for (int r = 0; r < 4; ++r) {
            int el = row0 + mf * 16 + g * 4 + r;
            int ep = eb + el;
            if (ep < EE) {
                float sc = scale_s[el];
                HeB[(size_t)ep * SS + l15]      = f32_to_bf16_rne(he[mf][0][r] * sc);
                HeB[(size_t)ep * SS + 16 + l15] = f32_to_bf16_rne(he[mf][1][r] * sc);
            }
        }
#undef STAGE_H
#undef SYNCPT
}

// ---------------- K_reduce_out: H2 = cnt*R + segsum(He); out = log_softmax(H2@Wout+bout) ----------------
__global__ void k_reduce_out(const unsigned short* __restrict__ HeB, const int* __restrict__ rowptr,
                             const float* __restrict__ R, const float* __restrict__ Wout,
                             const float* __restrict__ bout, float* __restrict__ out) {
    __shared__ float h2[8][33];
    __shared__ float lgS[8][10];
    __shared__ float lseS[8];
    int tid = threadIdx.x;
    int un8 = tid >> 5, s = tid & 31;
    int u = blockIdx.x * 8 + un8;
    int p0 = rowptr[u], p1 = rowptr[u + 1];
    float acc = (float)(p1 - p0) * R[u * SS + s];
    for (int p = p0; p < p1; ++p)
        acc += bf16_to_f32(HeB[(size_t)p * SS + s]);
    h2[un8][s] = acc;
    __syncthreads();
    if (tid < 80) {
        int un = tid / 10, c = tid - un * 10;
        float a = bout[c];
        #pragma unroll
        for (int s2 = 0; s2 < SS; ++s2) a += h2[un][s2] * Wout[s2 * CC + c];
        lgS[un][c] = a;
    }
    __syncthreads();
    if (tid < 8) {
        float mx = lgS[tid][0];
        #pragma unroll
        for (int c = 1; c < CC; ++c) mx = fmaxf(mx, lgS[tid][c]);
        float se = 0.f;
        #pragma unroll
        for (int c = 0; c < CC; ++c)
            se += __builtin_amdgcn_exp2f((lgS[tid][c] - mx) * 1.4426950408889634f);
        lseS[tid] = mx + __builtin_amdgcn_logf(se) * 0.6931471805599453f;
    }
    __syncthreads();
    if (tid < 80) {
        int un = tid / 10, c = tid - un * 10;
        out[(size_t)(blockIdx.x * 8 + un) * CC + c] = lgS[un][c] - lseS[un];
    }
}

extern "C" void kernel_launch(void* const* d_in, const int* in_sizes, int n_in,
                              void* d_out, int out_size, void* d_ws, size_t ws_size,
                              hipStream_t stream) {
    const float* feat = (const float*)d_in[0];
    const int*   Xn   = (const int*)d_in[1];
    const int*   Xe   = (const int*)d_in[2];
    const float* dg   = (const float*)d_in[3];
    const float* Wxi  = (const float*)d_in[4];
    const float* bxi  = (const float*)d_in[5];
    const float* Wrou = (const float*)d_in[6];
    const float* brou = (const float*)d_in[7];
    const float* Wout = (const float*)d_in[8];
    const float* bout = (const float*)d_in[9];
    float* out = (float*)d_out;

    char* ws = (char*)d_ws;
    unsigned short* featB  = (unsigned short*)(ws);                      // 12,800,000
    unsigned short* WxiB   = (unsigned short*)(ws + 12800000);           //    524,288
    unsigned short* HeB    = (unsigned short*)(ws + 13324288);           // 12,800,000
    float*          R      = (float*)(ws + 26124288);                    //  6,400,000
    int*            perm   = (int*)(ws + 32524288);                      //    800,000
    int*            rowptr = (int*)(ws + 33324288);                      //    200,064
    int*            cursor = (int*)(ws + 33524352);                      //    200,000
    int*            cnt    = (int*)(ws + 33724352);                      //    200,000
    unsigned int*   flags  = (unsigned int*)(ws + 33924352);             //      1,024
    float*          bxiT   = (float*)(ws + 33925376);                    //      4,096

    hipMemsetAsync(cnt, 0, 201024, stream);                              // cnt + flags

    k_prep      <<<14307, 256, 0, stream>>>(feat, featB, Wxi, WxiB, bxi, bxiT, Xn, cnt,
                                            Wrou, brou, R);
    k_scan_lb   <<<196, 256, 0, stream>>>(cnt, rowptr, cursor, flags);
    k_scatter   <<<782, 256, 0, stream>>>(Xn, cursor, perm);
    k_edge_gemm <<<(EE + 127) / 128, 256, 0, stream>>>(featB, WxiB, Xn, Xe, dg, bxiT, perm, R, rowptr, HeB);
    k_reduce_out<<<VV / 8, 256, 0, stream>>>(HeB, rowptr, R, Wout, bout, out);
}